// Round 9
// baseline (418.265 us; speedup 1.0000x reference)
//
#include <hip/hip_runtime.h>
#include <hip/hip_fp16.h>

#define NN 50000
#define EE 800000
#define BB 512
#define DIN 128
#define HH 64
#define DOUT 32
#define BN_EPS 1e-5f
#define SCAN_BLOCKS 196   // ceil(50000/256)
#define GATHER_BLOCKS 2048
#define PADMAX (16 * NN + EE + 64)   // worst-case padded CSR entries

typedef unsigned int u32x4 __attribute__((ext_vector_type(4)));

// ---------------- proj: planar Qh = half(X @ W)  (layer 0 only) ----------------
template <int CIN>
__global__ __launch_bounds__(256) void proj_kernel(const float* __restrict__ X,
                                                   const float* __restrict__ W,  // [CIN][64]
                                                   __half2* __restrict__ QhA,    // [N+1][16] cols 0..31
                                                   __half2* __restrict__ QhB)    // [N+1][16] cols 32..63
{
    __shared__ float sW[CIN * 64];
    __shared__ float sX[16 * CIN];
    const int tid = threadIdx.x;
    const int row0 = blockIdx.x * 16;

    for (int i = tid; i < CIN * 16; i += 256)
        ((float4*)sW)[i] = ((const float4*)W)[i];
    const float* Xb = X + (size_t)row0 * CIN;
    for (int i = tid; i < 16 * CIN / 4; i += 256)
        ((float4*)sX)[i] = ((const float4*)Xb)[i];
    __syncthreads();

    const int col2 = tid & 31;   // column pair {2c,2c+1}
    const int rg   = tid >> 5;   // 0..7 -> rows rg*2, rg*2+1
    float2 acc0 = {0.f, 0.f};
    float2 acc1 = {0.f, 0.f};
    const float* x0p = &sX[(rg * 2 + 0) * CIN];
    const float* x1p = &sX[(rg * 2 + 1) * CIN];
#pragma unroll 4
    for (int k = 0; k < CIN; ++k) {
        const float2 w = *(const float2*)&sW[k * 64 + col2 * 2];
        const float x0 = x0p[k];
        const float x1 = x1p[k];
        acc0.x = fmaf(x0, w.x, acc0.x);
        acc0.y = fmaf(x0, w.y, acc0.y);
        acc1.x = fmaf(x1, w.x, acc1.x);
        acc1.y = fmaf(x1, w.y, acc1.y);
    }
    const int r0 = row0 + rg * 2;
    __half2* plane = (col2 < 16) ? QhA : QhB;
    const int pc = col2 & 15;
    plane[(size_t)(r0 + 0) * 16 + pc] = __floats2half2_rn(acc0.x, acc0.y);
    plane[(size_t)(r0 + 1) * 16 + pc] = __floats2half2_rn(acc1.x, acc1.y);
}

// ---------------- padded-CSR build ----------------
__global__ __launch_bounds__(256) void fill_kernel(unsigned int* __restrict__ dstw,
                                                   int* __restrict__ deg)
{
    const int i = blockIdx.x * 256 + threadIdx.x;
    if (i < PADMAX / 2) dstw[i] = 0xC350C350u;  // NN = 50000 = 0xC350 in both halves
    if (i < NN) deg[i] = 0;
}

__global__ __launch_bounds__(256) void hist_rank_kernel(const int* __restrict__ dst,
                                                        int* __restrict__ deg,
                                                        unsigned short* __restrict__ rank)
{
    const int e = blockIdx.x * 256 + threadIdx.x;  // exactly E threads
    rank[e] = (unsigned short)atomicAdd(&deg[dst[e]], 1);
}

// scan over padded capacities cap = max(16, roundup16(deg))
__global__ __launch_bounds__(256) void scanA_kernel(const int* __restrict__ deg,
                                                    int* __restrict__ poffs,
                                                    int* __restrict__ blockSums)
{
    __shared__ int s[256];
    const int t = threadIdx.x;
    const int i = blockIdx.x * 256 + t;
    int v = 0;
    if (i < NN) {
        const int d = deg[i];
        v = (d <= 16) ? 16 : ((d + 15) & ~15);
    }
    s[t] = v;
    __syncthreads();
    for (int off = 1; off < 256; off <<= 1) {
        const int a = (t >= off) ? s[t - off] : 0;
        __syncthreads();
        s[t] += a;
        __syncthreads();
    }
    if (i < NN) poffs[i] = s[t] - v;  // exclusive intra-block
    if (t == 255) blockSums[blockIdx.x] = s[255];
}

__global__ __launch_bounds__(256) void scanB_kernel(const int* __restrict__ blockSums,
                                                    int* __restrict__ blockOff,
                                                    int* __restrict__ poffs)
{
    __shared__ int s[256];
    const int t = threadIdx.x;
    const int v = (t < SCAN_BLOCKS) ? blockSums[t] : 0;
    s[t] = v;
    __syncthreads();
    for (int off = 1; off < 256; off <<= 1) {
        const int a = (t >= off) ? s[t - off] : 0;
        __syncthreads();
        s[t] += a;
        __syncthreads();
    }
    if (t < SCAN_BLOCKS) blockOff[t] = s[t] - v;  // exclusive
    if (t == SCAN_BLOCKS - 1) poffs[NN] = s[t];   // total padded size
}

__global__ __launch_bounds__(256) void scanC_kernel(int* __restrict__ poffs,
                                                    const int* __restrict__ blockOff,
                                                    float* __restrict__ statsbuf,   // 384 floats
                                                    float* __restrict__ pooled,     // B*64
                                                    unsigned int* __restrict__ qzA, // QhA row NN
                                                    unsigned int* __restrict__ qzB) // QhB row NN
{
    const int i = blockIdx.x * 256 + threadIdx.x;
    if (i < NN) poffs[i] += blockOff[blockIdx.x];
    if (i < 384) statsbuf[i] = 0.f;
    if (i < BB * 64) pooled[i] = 0.f;
    if (blockIdx.x == 1 && threadIdx.x < 16) qzA[threadIdx.x] = 0u;
    if (blockIdx.x == 2 && threadIdx.x < 16) qzB[threadIdx.x] = 0u;
}

__global__ __launch_bounds__(256) void scatter_kernel(const int* __restrict__ src,
                                                      const int* __restrict__ dst,
                                                      const unsigned short* __restrict__ rank,
                                                      const int* __restrict__ poffs,
                                                      unsigned short* __restrict__ srcPadded)
{
    const int e = blockIdx.x * 256 + threadIdx.x;  // exactly E threads
    const int pos = poffs[dst[e]] + (int)rank[e];
    srcPadded[pos] = (unsigned short)src[e];
}

// ---------------- gather (per plane): Z-half = Q[n] + b1 + sum_src Q[src]; fused half-stats --------
// Plane = 3.2MB -> L2-resident per XCD. 16 lanes per 64B row, 4 edges per load instruction.
// Streaming data (poffs, srcPadded, Z) uses nontemporal ops so the plane stays cached.
template <int PLANE>
__global__ __launch_bounds__(256) void gather_kernel(const __half2* __restrict__ Qp,
                                                     const int* __restrict__ poffs,
                                                     const unsigned short* __restrict__ srcPadded,
                                                     const float* __restrict__ b1,
                                                     float* __restrict__ Z,
                                                     float* __restrict__ sums,   // [64]
                                                     float* __restrict__ sumsq)  // [64]
{
    const int tid  = threadIdx.x;
    const int lane = tid & 63;
    const int wid  = tid >> 6;       // wave in block: 0..3
    const int c    = lane & 15;      // dword (column pair) within 64B row
    const int grp  = lane >> 4;      // 0..3: edge slot
    const int wsel = grp >> 1;       // word offset within uint4
    const int sh   = (grp & 1) << 4; // shift for ushort extraction
    const uint* Qd = (const uint*)Qp;   // 16 dwords per row
    const float2 bb = ((const float2*)b1)[PLANE * 16 + c];

    float2 sa = {0.f, 0.f};
    float2 ta = {0.f, 0.f};
    const int step = GATHER_BLOCKS * 4;

    int node = blockIdx.x * 4 + wid;  // < 8192 < NN always
    // prefetch first node
    int p0 = __builtin_nontemporal_load(poffs + node);
    int p1 = __builtin_nontemporal_load(poffs + node + 1);
    u32x4 ia = __builtin_nontemporal_load((const u32x4*)(srcPadded + p0));
    u32x4 ib = __builtin_nontemporal_load((const u32x4*)(srcPadded + p0 + 8));
    bool two = (p1 - p0) > 16;
    u32x4 ia2 = {0, 0, 0, 0}, ib2 = {0, 0, 0, 0};
    if (two) {
        ia2 = __builtin_nontemporal_load((const u32x4*)(srcPadded + p0 + 16));
        ib2 = __builtin_nontemporal_load((const u32x4*)(srcPadded + p0 + 24));
    }
    uint sr = Qd[(size_t)node * 16 + c];

    while (true) {
        // issue row loads for current node (4 per 16-edge chunk)
        uint r[8];
        {
            const uint i0 = (ia[wsel] >> sh) & 0xffffu;
            const uint i1 = (ia[2 + wsel] >> sh) & 0xffffu;
            const uint i2 = (ib[wsel] >> sh) & 0xffffu;
            const uint i3 = (ib[2 + wsel] >> sh) & 0xffffu;
            r[0] = Qd[(size_t)i0 * 16 + c];
            r[1] = Qd[(size_t)i1 * 16 + c];
            r[2] = Qd[(size_t)i2 * 16 + c];
            r[3] = Qd[(size_t)i3 * 16 + c];
        }
        if (two) {
            const uint i4 = (ia2[wsel] >> sh) & 0xffffu;
            const uint i5 = (ia2[2 + wsel] >> sh) & 0xffffu;
            const uint i6 = (ib2[wsel] >> sh) & 0xffffu;
            const uint i7 = (ib2[2 + wsel] >> sh) & 0xffffu;
            r[4] = Qd[(size_t)i4 * 16 + c];
            r[5] = Qd[(size_t)i5 * 16 + c];
            r[6] = Qd[(size_t)i6 * 16 + c];
            r[7] = Qd[(size_t)i7 * 16 + c];
        }

        // prefetch next node (overlaps with current row loads)
        const int nnode = node + step;
        const bool more = nnode < NN;
        int np0 = 0, np1 = 0;
        u32x4 nia = {0, 0, 0, 0}, nib = {0, 0, 0, 0};
        u32x4 nia2 = {0, 0, 0, 0}, nib2 = {0, 0, 0, 0};
        uint nsr = 0;
        bool ntwo = false;
        if (more) {
            np0 = __builtin_nontemporal_load(poffs + nnode);
            np1 = __builtin_nontemporal_load(poffs + nnode + 1);
            nia = __builtin_nontemporal_load((const u32x4*)(srcPadded + np0));
            nib = __builtin_nontemporal_load((const u32x4*)(srcPadded + np0 + 8));
            ntwo = (np1 - np0) > 16;
            if (ntwo) {
                nia2 = __builtin_nontemporal_load((const u32x4*)(srcPadded + np0 + 16));
                nib2 = __builtin_nontemporal_load((const u32x4*)(srcPadded + np0 + 24));
            }
            nsr = Qd[(size_t)nnode * 16 + c];
        }

        // accumulate current node
        float2 acc = {0.f, 0.f};
#pragma unroll
        for (int k = 0; k < 4; ++k) {
            const float2 p = __half22float2(*(const __half2*)&r[k]);
            acc.x += p.x;
            acc.y += p.y;
        }
        if (two) {
#pragma unroll
            for (int k = 4; k < 8; ++k) {
                const float2 p = __half22float2(*(const __half2*)&r[k]);
                acc.x += p.x;
                acc.y += p.y;
            }
        }
        // rare: degree > 32
        for (int j = p0 + 32; j < p1; j += 16) {
            const u32x4 ja = __builtin_nontemporal_load((const u32x4*)(srcPadded + j));
            const u32x4 jb = __builtin_nontemporal_load((const u32x4*)(srcPadded + j + 8));
            const uint i0 = (ja[wsel] >> sh) & 0xffffu;
            const uint i1 = (ja[2 + wsel] >> sh) & 0xffffu;
            const uint i2 = (jb[wsel] >> sh) & 0xffffu;
            const uint i3 = (jb[2 + wsel] >> sh) & 0xffffu;
            uint rr[4];
            rr[0] = Qd[(size_t)i0 * 16 + c];
            rr[1] = Qd[(size_t)i1 * 16 + c];
            rr[2] = Qd[(size_t)i2 * 16 + c];
            rr[3] = Qd[(size_t)i3 * 16 + c];
#pragma unroll
            for (int k = 0; k < 4; ++k) {
                const float2 p = __half22float2(*(const __half2*)&rr[k]);
                acc.x += p.x;
                acc.y += p.y;
            }
        }

        // combine the 4 edge slots
        acc.x += __shfl_xor(acc.x, 16);
        acc.y += __shfl_xor(acc.y, 16);
        acc.x += __shfl_xor(acc.x, 32);
        acc.y += __shfl_xor(acc.y, 32);

        if (grp == 0) {
            const float2 p = __half22float2(*(const __half2*)&sr);
            acc.x += p.x + bb.x;
            acc.y += p.y + bb.y;
            double* zp = (double*)&((float2*)Z)[(size_t)node * 32 + PLANE * 16 + c];
            __builtin_nontemporal_store(*(double*)&acc, zp);
            sa.x += acc.x; sa.y += acc.y;
            ta.x += acc.x * acc.x; ta.y += acc.y * acc.y;
        }

        if (!more) break;
        node = nnode; p0 = np0; p1 = np1;
        ia = nia; ib = nib; two = ntwo;
        if (two) { ia2 = nia2; ib2 = nib2; }
        sr = nsr;
    }

    // block-level stats reduce: 4 waves x 16 lanes x 4 values -> 64 atomics
    __shared__ float red[4][16][4];
    if (grp == 0) {
        float* rp = red[wid][c];
        rp[0] = sa.x; rp[1] = sa.y; rp[2] = ta.x; rp[3] = ta.y;
    }
    __syncthreads();
    if (tid < 64) {
        const int c2 = tid >> 2;   // 0..15
        const int k  = tid & 3;    // 0..3
        const float v = red[0][c2][k] + red[1][c2][k] + red[2][c2][k] + red[3][c2][k];
        float* dstp;
        if (k == 0)      dstp = &sums[PLANE * 32 + 2 * c2 + 0];
        else if (k == 1) dstp = &sums[PLANE * 32 + 2 * c2 + 1];
        else if (k == 2) dstp = &sumsq[PLANE * 32 + 2 * c2 + 0];
        else             dstp = &sumsq[PLANE * 32 + 2 * c2 + 1];
        atomicAdd(dstp, v);
    }
}

// ---------------- fused: Qh_next = half( relu( relu(BN(Z)) @ W2 + b2 ) @ W1next ) ----------------
__global__ __launch_bounds__(256) void gemm2proj_kernel(const float* __restrict__ Z,
                                                        const float* __restrict__ sums,
                                                        const float* __restrict__ sumsq,
                                                        const float* __restrict__ g1,
                                                        const float* __restrict__ bt1,
                                                        const float* __restrict__ W2,   // [64][64]
                                                        const float* __restrict__ b2,
                                                        const float* __restrict__ W1n,  // [64][64]
                                                        __half2* __restrict__ QhA,
                                                        __half2* __restrict__ QhB)
{
    __shared__ float sW2[64 * 64];
    __shared__ float sW1[64 * 64];
    __shared__ float sH[16 * 64];
    __shared__ float sA[16 * 64];
    __shared__ float sScale[64];
    __shared__ float sShift[64];
    const int tid = threadIdx.x;
    const int row0 = blockIdx.x * 16;

    if (tid < 64) {
        const float inv_n = 1.0f / (float)NN;
        const float mean = sums[tid] * inv_n;
        const float var = fmaxf(sumsq[tid] * inv_n - mean * mean, 0.f);
        const float sc = g1[tid] * rsqrtf(var + BN_EPS);
        sScale[tid] = sc;
        sShift[tid] = bt1[tid] - mean * sc;
    }
    for (int i = tid; i < 1024; i += 256) {
        ((float4*)sW2)[i] = ((const float4*)W2)[i];
        ((float4*)sW1)[i] = ((const float4*)W1n)[i];
    }
    __syncthreads();

    const float4* Zb = (const float4*)(Z + (size_t)row0 * 64);
    {
        const int i = tid;  // 256 float4s = 16 rows x 16
        const float4 z = Zb[i];
        const int c4 = i & 15;
        const float4 sc = ((const float4*)sScale)[c4];
        const float4 sh = ((const float4*)sShift)[c4];
        float4 h;
        h.x = fmaxf(fmaf(z.x, sc.x, sh.x), 0.f);
        h.y = fmaxf(fmaf(z.y, sc.y, sh.y), 0.f);
        h.z = fmaxf(fmaf(z.z, sc.z, sh.z), 0.f);
        h.w = fmaxf(fmaf(z.w, sc.w, sh.w), 0.f);
        ((float4*)sH)[i] = h;
    }
    __syncthreads();

    // A = relu(H @ W2 + b2) -> sA
    {
        const int col = tid & 63;
        const int r0  = tid >> 6;
        const float bc = b2[col];
        float acc[4] = {bc, bc, bc, bc};
        for (int k = 0; k < 64; k += 4) {
            const float w0 = sW2[(k + 0) * 64 + col];
            const float w1 = sW2[(k + 1) * 64 + col];
            const float w2 = sW2[(k + 2) * 64 + col];
            const float w3 = sW2[(k + 3) * 64 + col];
#pragma unroll
            for (int rr = 0; rr < 4; ++rr) {
                const float4 hv = *(const float4*)&sH[(r0 + rr * 4) * 64 + k];
                acc[rr] = fmaf(hv.x, w0, acc[rr]);
                acc[rr] = fmaf(hv.y, w1, acc[rr]);
                acc[rr] = fmaf(hv.z, w2, acc[rr]);
                acc[rr] = fmaf(hv.w, w3, acc[rr]);
            }
        }
#pragma unroll
        for (int rr = 0; rr < 4; ++rr)
            sA[(r0 + rr * 4) * 64 + col] = fmaxf(acc[rr], 0.f);
    }
    __syncthreads();

    // Qh = half(A @ W1n), planar output
    {
        const int col2 = tid & 31;   // column pair
        const int rg   = tid >> 5;   // 0..7 -> rows rg*2, rg*2+1
        float2 acc0 = {0.f, 0.f};
        float2 acc1 = {0.f, 0.f};
        const float* a0p = &sA[(rg * 2 + 0) * 64];
        const float* a1p = &sA[(rg * 2 + 1) * 64];
#pragma unroll 4
        for (int k = 0; k < 64; ++k) {
            const float2 w = *(const float2*)&sW1[k * 64 + col2 * 2];
            const float a0 = a0p[k];
            const float a1 = a1p[k];
            acc0.x = fmaf(a0, w.x, acc0.x);
            acc0.y = fmaf(a0, w.y, acc0.y);
            acc1.x = fmaf(a1, w.x, acc1.x);
            acc1.y = fmaf(a1, w.y, acc1.y);
        }
        const int r0 = row0 + rg * 2;
        __half2* plane = (col2 < 16) ? QhA : QhB;
        const int pc = col2 & 15;
        plane[(size_t)(r0 + 0) * 16 + pc] = __floats2half2_rn(acc0.x, acc0.y);
        plane[(size_t)(r0 + 1) * 16 + pc] = __floats2half2_rn(acc1.x, acc1.y);
    }
}

// ---------------- gemm2 (pool epilogue, last layer) ----------------
__global__ __launch_bounds__(256) void gemm2pool_kernel(const float* __restrict__ Z,
                                                        const float* __restrict__ sums,
                                                        const float* __restrict__ sumsq,
                                                        const float* __restrict__ g1,
                                                        const float* __restrict__ bt1,
                                                        const float* __restrict__ W2,  // [64][64]
                                                        const float* __restrict__ b2,
                                                        const int* __restrict__ batch,
                                                        float* __restrict__ out)       // pooled [B][64]
{
    __shared__ float sW[64 * 64];
    __shared__ float sH[16 * 64];
    __shared__ float sScale[64];
    __shared__ float sShift[64];
    const int tid = threadIdx.x;
    const int row0 = blockIdx.x * 16;

    if (tid < 64) {
        const float inv_n = 1.0f / (float)NN;
        const float mean = sums[tid] * inv_n;
        const float var = fmaxf(sumsq[tid] * inv_n - mean * mean, 0.f);
        const float sc = g1[tid] * rsqrtf(var + BN_EPS);
        sScale[tid] = sc;
        sShift[tid] = bt1[tid] - mean * sc;
    }
    for (int i = tid; i < 1024; i += 256)
        ((float4*)sW)[i] = ((const float4*)W2)[i];
    __syncthreads();

    const float4* Zb = (const float4*)(Z + (size_t)row0 * 64);
    {
        const int i = tid;
        const float4 z = Zb[i];
        const int c4 = i & 15;
        const float4 sc = ((const float4*)sScale)[c4];
        const float4 sh = ((const float4*)sShift)[c4];
        float4 h;
        h.x = fmaxf(fmaf(z.x, sc.x, sh.x), 0.f);
        h.y = fmaxf(fmaf(z.y, sc.y, sh.y), 0.f);
        h.z = fmaxf(fmaf(z.z, sc.z, sh.z), 0.f);
        h.w = fmaxf(fmaf(z.w, sc.w, sh.w), 0.f);
        ((float4*)sH)[i] = h;
    }
    __syncthreads();

    const int col = tid & 63;
    const int r0  = tid >> 6;
    const float bc = b2[col];
    float acc[4] = {bc, bc, bc, bc};
    for (int k = 0; k < 64; k += 4) {
        const float w0 = sW[(k + 0) * 64 + col];
        const float w1 = sW[(k + 1) * 64 + col];
        const float w2 = sW[(k + 2) * 64 + col];
        const float w3 = sW[(k + 3) * 64 + col];
#pragma unroll
        for (int rr = 0; rr < 4; ++rr) {
            const float4 hv = *(const float4*)&sH[(r0 + rr * 4) * 64 + k];
            acc[rr] = fmaf(hv.x, w0, acc[rr]);
            acc[rr] = fmaf(hv.y, w1, acc[rr]);
            acc[rr] = fmaf(hv.z, w2, acc[rr]);
            acc[rr] = fmaf(hv.w, w3, acc[rr]);
        }
    }
#pragma unroll
    for (int rr = 0; rr < 4; ++rr) {
        const int row = row0 + r0 + rr * 4;
        const float v = fmaxf(acc[rr], 0.f);
        atomicAdd(&out[(size_t)batch[row] * 64 + col], v);
    }
}

// ---------------- final MLP: out = relu(P @ fW1 + fb1) @ fW2 + fb2 ----------------
__global__ __launch_bounds__(256) void final_mlp(const float* __restrict__ P,   // [512][64]
                                                 const float* __restrict__ W1,  // [64][64]
                                                 const float* __restrict__ b1,
                                                 const float* __restrict__ W2,  // [64][32]
                                                 const float* __restrict__ b2,
                                                 float* __restrict__ out)       // [512][32]
{
    __shared__ float sW1[64 * 64];
    __shared__ float sW2[64 * 32];
    __shared__ float sH[4 * 64];
    const int tid = threadIdx.x;
    const int row0 = blockIdx.x * 4;

    for (int i = tid; i < 1024; i += 256) ((float4*)sW1)[i] = ((const float4*)W1)[i];
    for (int i = tid; i < 512; i += 256) ((float4*)sW2)[i] = ((const float4*)W2)[i];
    __syncthreads();

    const int col = tid & 63;
    const int r = tid >> 6;
    float acc = b1[col];
    const float* prow = P + (size_t)(row0 + r) * 64;
    for (int k = 0; k < 64; ++k) acc = fmaf(prow[k], sW1[k * 64 + col], acc);
    sH[r * 64 + col] = fmaxf(acc, 0.f);
    __syncthreads();

    if (tid < 128) {
        const int c = tid & 31;
        const int r2 = tid >> 5;
        float a2 = b2[c];
        for (int k = 0; k < 64; ++k) a2 = fmaf(sH[r2 * 64 + k], sW2[k * 32 + c], a2);
        out[(size_t)(row0 + r2) * 32 + c] = a2;
    }
}

extern "C" void kernel_launch(void* const* d_in, const int* in_sizes, int n_in,
                              void* d_out, int out_size, void* d_ws, size_t ws_size,
                              hipStream_t stream)
{
    const float* x   = (const float*)d_in[0];
    const int* ei    = (const int*)d_in[1];   // [2][E]: first E = src, next E = dst
    const int* batch = (const int*)d_in[2];
    const float* cW1[3] = {(const float*)d_in[4],  (const float*)d_in[10], (const float*)d_in[16]};
    const float* cb1[3] = {(const float*)d_in[5],  (const float*)d_in[11], (const float*)d_in[17]};
    const float* cg1[3] = {(const float*)d_in[6],  (const float*)d_in[12], (const float*)d_in[18]};
    const float* cbt[3] = {(const float*)d_in[7],  (const float*)d_in[13], (const float*)d_in[19]};
    const float* cW2[3] = {(const float*)d_in[8],  (const float*)d_in[14], (const float*)d_in[20]};
    const float* cb2[3] = {(const float*)d_in[9],  (const float*)d_in[15], (const float*)d_in[21]};
    const float* fW1 = (const float*)d_in[22];
    const float* fb1 = (const float*)d_in[23];
    const float* fW2 = (const float*)d_in[24];
    const float* fb2 = (const float*)d_in[25];
    float* out = (float*)d_out;

    // workspace layout
    float* bufX     = (float*)d_ws;                        // N*64 fp32: Z buffer
    __half2* QhA    = (__half2*)(bufX + (size_t)NN * 64);  // (N+1)*16 half2, cols 0..31
    __half2* QhB    = QhA + (size_t)(NN + 1) * 16;         // (N+1)*16 half2, cols 32..63
    float* pooled   = (float*)(QhB + (size_t)(NN + 1) * 16);  // B*64
    float* statsbuf = pooled + (size_t)BB * 64;            // 3 layers x (64 sums + 64 sumsq)
    int* deg        = (int*)(statsbuf + 384);              // N
    int* poffs      = deg + NN;                            // N+1 (padded offsets)
    int* blockSums  = poffs + (NN + 1);                    // 256
    int* blockOff   = blockSums + 256;                     // 256
    uintptr_t pa = ((uintptr_t)(blockOff + 256) + 15) & ~(uintptr_t)15;
    unsigned short* srcPadded = (unsigned short*)pa;       // PADMAX (16B aligned)
    unsigned short* rank      = srcPadded + PADMAX;        // E

    const int* esrc = ei;
    const int* edst = ei + EE;

    const int gemm_blocks = NN / 16;   // 3125
    const int edge_blocks = EE / 256;  // 3125

    // ---- build padded CSR by dst ----
    fill_kernel<<<(PADMAX / 2 + 255) / 256, 256, 0, stream>>>((unsigned int*)srcPadded, deg);
    hist_rank_kernel<<<edge_blocks, 256, 0, stream>>>(edst, deg, rank);
    scanA_kernel<<<SCAN_BLOCKS, 256, 0, stream>>>(deg, poffs, blockSums);
    scanB_kernel<<<1, 256, 0, stream>>>(blockSums, blockOff, poffs);
    scanC_kernel<<<SCAN_BLOCKS, 256, 0, stream>>>(poffs, blockOff, statsbuf, pooled,
                                                  (unsigned int*)(QhA + (size_t)NN * 16),
                                                  (unsigned int*)(QhB + (size_t)NN * 16));
    scatter_kernel<<<edge_blocks, 256, 0, stream>>>(esrc, edst, rank, poffs, srcPadded);

    // layer 0 projection
    proj_kernel<DIN><<<gemm_blocks, 256, 0, stream>>>(x, cW1[0], QhA, QhB);

    for (int layer = 0; layer < 3; ++layer) {
        float* sums  = statsbuf + layer * 128;
        float* sumsq = sums + 64;

        // gather-aggregate per plane + fused BN half-stats
        gather_kernel<0><<<GATHER_BLOCKS, 256, 0, stream>>>(QhA, poffs, srcPadded, cb1[layer],
                                                            bufX, sums, sumsq);
        gather_kernel<1><<<GATHER_BLOCKS, 256, 0, stream>>>(QhB, poffs, srcPadded, cb1[layer],
                                                            bufX, sums, sumsq);

        if (layer < 2) {
            gemm2proj_kernel<<<gemm_blocks, 256, 0, stream>>>(bufX, sums, sumsq, cg1[layer],
                                                              cbt[layer], cW2[layer], cb2[layer],
                                                              cW1[layer + 1], QhA, QhB);
        } else {
            gemm2pool_kernel<<<gemm_blocks, 256, 0, stream>>>(bufX, sums, sumsq, cg1[layer],
                                                              cbt[layer], cW2[layer], cb2[layer],
                                                              batch, pooled);
        }
    }

    // final MLP on pooled graph features
    final_mlp<<<BB / 4, 256, 0, stream>>>(pooled, fW1, fb1, fW2, fb2, out);
}

// Round 10
// 377.465 us; speedup vs baseline: 1.1081x; 1.1081x over previous
//
#include <hip/hip_runtime.h>
#include <hip/hip_fp16.h>

#define NN 50000
#define EE 800000
#define BB 512
#define DIN 128
#define HH 64
#define DOUT 32
#define BN_EPS 1e-5f
#define SCAN_BLOCKS 196   // ceil(50000/256)
#define GATHER_BLOCKS 2048
#define PADMAX (16 * NN + EE + 64)   // worst-case padded CSR entries

typedef float f32x4 __attribute__((ext_vector_type(4)));
typedef unsigned int u32x4 __attribute__((ext_vector_type(4)));

// ---------------- proj: Qh = half(X @ W)  (layer 0 only) ----------------
template <int CIN>
__global__ __launch_bounds__(256) void proj_kernel(const float* __restrict__ X,
                                                   const float* __restrict__ W,  // [CIN][64]
                                                   __half2* __restrict__ Qh)     // [N+1][32]
{
    __shared__ float sW[CIN * 64];
    __shared__ float sX[16 * CIN];
    const int tid = threadIdx.x;
    const int row0 = blockIdx.x * 16;

    for (int i = tid; i < CIN * 16; i += 256)
        ((float4*)sW)[i] = ((const float4*)W)[i];
    const float* Xb = X + (size_t)row0 * CIN;
    for (int i = tid; i < 16 * CIN / 4; i += 256)
        ((float4*)sX)[i] = ((const float4*)Xb)[i];
    __syncthreads();

    const int col2 = tid & 31;   // column pair
    const int rg   = tid >> 5;   // 0..7 -> rows rg*2, rg*2+1
    float2 acc0 = {0.f, 0.f};
    float2 acc1 = {0.f, 0.f};
    const float* x0p = &sX[(rg * 2 + 0) * CIN];
    const float* x1p = &sX[(rg * 2 + 1) * CIN];
#pragma unroll 4
    for (int k = 0; k < CIN; ++k) {
        const float2 w = *(const float2*)&sW[k * 64 + col2 * 2];
        const float x0 = x0p[k];
        const float x1 = x1p[k];
        acc0.x = fmaf(x0, w.x, acc0.x);
        acc0.y = fmaf(x0, w.y, acc0.y);
        acc1.x = fmaf(x1, w.x, acc1.x);
        acc1.y = fmaf(x1, w.y, acc1.y);
    }
    const int r0 = row0 + rg * 2;
    Qh[(size_t)(r0 + 0) * 32 + col2] = __floats2half2_rn(acc0.x, acc0.y);
    Qh[(size_t)(r0 + 1) * 32 + col2] = __floats2half2_rn(acc1.x, acc1.y);
}

// ---------------- padded-CSR build ----------------
__global__ __launch_bounds__(256) void fill_kernel(unsigned int* __restrict__ dstw,
                                                   int* __restrict__ deg)
{
    const int i = blockIdx.x * 256 + threadIdx.x;
    if (i < PADMAX / 2) __builtin_nontemporal_store(0xC350C350u, dstw + i);  // NN=50000=0xC350
    if (i < NN) deg[i] = 0;
}

__global__ __launch_bounds__(256) void hist_rank_kernel(const int* __restrict__ dst,
                                                        int* __restrict__ deg,
                                                        unsigned short* __restrict__ rank)
{
    const int e = blockIdx.x * 256 + threadIdx.x;  // exactly E threads
    const int d = __builtin_nontemporal_load(dst + e);
    const unsigned short r = (unsigned short)atomicAdd(&deg[d], 1);
    __builtin_nontemporal_store(r, rank + e);
}

// scan over padded capacities cap = max(16, roundup16(deg))
__global__ __launch_bounds__(256) void scanA_kernel(const int* __restrict__ deg,
                                                    int* __restrict__ poffs,
                                                    int* __restrict__ blockSums)
{
    __shared__ int s[256];
    const int t = threadIdx.x;
    const int i = blockIdx.x * 256 + t;
    int v = 0;
    if (i < NN) {
        const int d = deg[i];
        v = (d <= 16) ? 16 : ((d + 15) & ~15);
    }
    s[t] = v;
    __syncthreads();
    for (int off = 1; off < 256; off <<= 1) {
        const int a = (t >= off) ? s[t - off] : 0;
        __syncthreads();
        s[t] += a;
        __syncthreads();
    }
    if (i < NN) poffs[i] = s[t] - v;  // exclusive intra-block
    if (t == 255) blockSums[blockIdx.x] = s[255];
}

__global__ __launch_bounds__(256) void scanB_kernel(const int* __restrict__ blockSums,
                                                    int* __restrict__ blockOff,
                                                    int* __restrict__ poffs)
{
    __shared__ int s[256];
    const int t = threadIdx.x;
    const int v = (t < SCAN_BLOCKS) ? blockSums[t] : 0;
    s[t] = v;
    __syncthreads();
    for (int off = 1; off < 256; off <<= 1) {
        const int a = (t >= off) ? s[t - off] : 0;
        __syncthreads();
        s[t] += a;
        __syncthreads();
    }
    if (t < SCAN_BLOCKS) blockOff[t] = s[t] - v;  // exclusive
    if (t == SCAN_BLOCKS - 1) poffs[NN] = s[t];   // total padded size
}

__global__ __launch_bounds__(256) void scanC_kernel(int* __restrict__ poffs,
                                                    const int* __restrict__ blockOff,
                                                    float* __restrict__ statsbuf,  // 384 floats
                                                    float* __restrict__ pooled,    // B*64
                                                    unsigned int* __restrict__ qzero)  // Qh row NN
{
    const int i = blockIdx.x * 256 + threadIdx.x;
    if (i < NN) poffs[i] += blockOff[blockIdx.x];
    if (i < 384) statsbuf[i] = 0.f;
    if (i < BB * 64) pooled[i] = 0.f;
    if (blockIdx.x == 1 && threadIdx.x < 32) qzero[threadIdx.x] = 0u;
}

__global__ __launch_bounds__(256) void scatter_kernel(const int* __restrict__ src,
                                                      const int* __restrict__ dst,
                                                      const unsigned short* __restrict__ rank,
                                                      const int* __restrict__ poffs,
                                                      unsigned short* __restrict__ srcPadded)
{
    const int e = blockIdx.x * 256 + threadIdx.x;  // exactly E threads
    const int d = __builtin_nontemporal_load(dst + e);
    const int s = __builtin_nontemporal_load(src + e);
    const int r = (int)__builtin_nontemporal_load(rank + e);
    const int pos = poffs[d] + r;
    srcPadded[pos] = (unsigned short)s;
}

// ---------------- gather: Z[n] = Q[n] + b1 + sum_{src} Q[src]; fused BN column stats ----------------
// 16 lanes per 128B row (uint2 = 8B/lane), grp=lane>>4 picks among 4 edges/instruction.
// Padded CSR (chunk 16, pad idx = NN zero row), 2-node pipeline (idx/self prefetch overlaps rows),
// nontemporal streaming (poffs/srcPadded/Z) so Q keeps the L2.
__global__ __launch_bounds__(256) void gather_kernel(const __half2* __restrict__ Qh,
                                                     const int* __restrict__ poffs,
                                                     const unsigned short* __restrict__ srcPadded,
                                                     const float* __restrict__ b1,
                                                     float* __restrict__ Z,
                                                     float* __restrict__ sums,   // [64]
                                                     float* __restrict__ sumsq)  // [64]
{
    const int tid  = threadIdx.x;
    const int lane = tid & 63;
    const int wid  = tid >> 6;      // wave in block: 0..3
    const int colq = lane & 15;     // uint2 (4 halfs = 8B) within row
    const int grp  = lane >> 4;     // 0..3: edge slot
    const uint2* Qr = (const uint2*)Qh;  // 16 uint2 per row
    const float4 bb = ((const float4*)b1)[colq];

    float sa0 = 0.f, sa1 = 0.f, sa2 = 0.f, sa3 = 0.f;
    float ta0 = 0.f, ta1 = 0.f, ta2 = 0.f, ta3 = 0.f;
    const int step = GATHER_BLOCKS * 4;

    int node = blockIdx.x * 4 + wid;  // < 8192 < NN always
    int p0 = __builtin_nontemporal_load(poffs + node);
    int p1 = __builtin_nontemporal_load(poffs + node + 1);
    int i0 = __builtin_nontemporal_load(srcPadded + p0 + grp);
    int i1 = __builtin_nontemporal_load(srcPadded + p0 + 4 + grp);
    int i2 = __builtin_nontemporal_load(srcPadded + p0 + 8 + grp);
    int i3 = __builtin_nontemporal_load(srcPadded + p0 + 12 + grp);
    bool two = (p1 - p0) > 16;
    int i4 = NN, i5 = NN, i6 = NN, i7 = NN;
    if (two) {
        i4 = __builtin_nontemporal_load(srcPadded + p0 + 16 + grp);
        i5 = __builtin_nontemporal_load(srcPadded + p0 + 20 + grp);
        i6 = __builtin_nontemporal_load(srcPadded + p0 + 24 + grp);
        i7 = __builtin_nontemporal_load(srcPadded + p0 + 28 + grp);
    }
    uint2 sr = Qr[(size_t)node * 16 + colq];

#define ACC4(r)                                                            \
    do {                                                                   \
        const float2 pA_ = __half22float2(*(const __half2*)&(r).x);        \
        const float2 pB_ = __half22float2(*(const __half2*)&(r).y);        \
        a0 += pA_.x; a1 += pA_.y; a2 += pB_.x; a3 += pB_.y;                \
    } while (0)

    while (true) {
        // issue row loads for current node
        const uint2 r0 = Qr[(size_t)i0 * 16 + colq];
        const uint2 r1 = Qr[(size_t)i1 * 16 + colq];
        const uint2 r2 = Qr[(size_t)i2 * 16 + colq];
        const uint2 r3 = Qr[(size_t)i3 * 16 + colq];
        uint2 r4, r5, r6, r7;
        if (two) {
            r4 = Qr[(size_t)i4 * 16 + colq];
            r5 = Qr[(size_t)i5 * 16 + colq];
            r6 = Qr[(size_t)i6 * 16 + colq];
            r7 = Qr[(size_t)i7 * 16 + colq];
        }

        // prefetch next node (overlaps current row-load latency)
        const int nnode = node + step;
        const bool more = nnode < NN;
        int np0 = 0, np1 = 0;
        int ni0 = NN, ni1 = NN, ni2 = NN, ni3 = NN, ni4 = NN, ni5 = NN, ni6 = NN, ni7 = NN;
        uint2 nsr = {0, 0};
        bool ntwo = false;
        if (more) {
            np0 = __builtin_nontemporal_load(poffs + nnode);
            np1 = __builtin_nontemporal_load(poffs + nnode + 1);
            ni0 = __builtin_nontemporal_load(srcPadded + np0 + grp);
            ni1 = __builtin_nontemporal_load(srcPadded + np0 + 4 + grp);
            ni2 = __builtin_nontemporal_load(srcPadded + np0 + 8 + grp);
            ni3 = __builtin_nontemporal_load(srcPadded + np0 + 12 + grp);
            ntwo = (np1 - np0) > 16;
            if (ntwo) {
                ni4 = __builtin_nontemporal_load(srcPadded + np0 + 16 + grp);
                ni5 = __builtin_nontemporal_load(srcPadded + np0 + 20 + grp);
                ni6 = __builtin_nontemporal_load(srcPadded + np0 + 24 + grp);
                ni7 = __builtin_nontemporal_load(srcPadded + np0 + 28 + grp);
            }
            nsr = Qr[(size_t)nnode * 16 + colq];
        }

        // accumulate current node
        float a0 = 0.f, a1 = 0.f, a2 = 0.f, a3 = 0.f;
        ACC4(r0); ACC4(r1); ACC4(r2); ACC4(r3);
        if (two) { ACC4(r4); ACC4(r5); ACC4(r6); ACC4(r7); }
        // rare: degree > 32
        for (int j = p0 + 32; j < p1; j += 16) {
            const int j0 = __builtin_nontemporal_load(srcPadded + j + grp);
            const int j1 = __builtin_nontemporal_load(srcPadded + j + 4 + grp);
            const int j2 = __builtin_nontemporal_load(srcPadded + j + 8 + grp);
            const int j3 = __builtin_nontemporal_load(srcPadded + j + 12 + grp);
            const uint2 q0 = Qr[(size_t)j0 * 16 + colq];
            const uint2 q1 = Qr[(size_t)j1 * 16 + colq];
            const uint2 q2 = Qr[(size_t)j2 * 16 + colq];
            const uint2 q3 = Qr[(size_t)j3 * 16 + colq];
            ACC4(q0); ACC4(q1); ACC4(q2); ACC4(q3);
        }

        // combine the 4 edge slots
        a0 += __shfl_xor(a0, 16); a1 += __shfl_xor(a1, 16);
        a2 += __shfl_xor(a2, 16); a3 += __shfl_xor(a3, 16);
        a0 += __shfl_xor(a0, 32); a1 += __shfl_xor(a1, 32);
        a2 += __shfl_xor(a2, 32); a3 += __shfl_xor(a3, 32);

        if (grp == 0) {
            const float2 pA = __half22float2(*(const __half2*)&sr.x);
            const float2 pB = __half22float2(*(const __half2*)&sr.y);
            a0 += pA.x + bb.x; a1 += pA.y + bb.y;
            a2 += pB.x + bb.z; a3 += pB.y + bb.w;
            f32x4 zv = {a0, a1, a2, a3};
            __builtin_nontemporal_store(zv, (f32x4*)Z + (size_t)node * 16 + colq);
            sa0 += a0; sa1 += a1; sa2 += a2; sa3 += a3;
            ta0 += a0 * a0; ta1 += a1 * a1; ta2 += a2 * a2; ta3 += a3 * a3;
        }

        if (!more) break;
        node = nnode; p0 = np0; p1 = np1; two = ntwo;
        i0 = ni0; i1 = ni1; i2 = ni2; i3 = ni3;
        i4 = ni4; i5 = ni5; i6 = ni6; i7 = ni7;
        sr = nsr;
    }
#undef ACC4

    // block-level stats reduce: 4 waves x 16 colq x 8 values -> 128 atomics
    __shared__ float red[4][16][8];
    if (grp == 0) {
        float* rp = red[wid][colq];
        rp[0] = sa0; rp[1] = sa1; rp[2] = sa2; rp[3] = sa3;
        rp[4] = ta0; rp[5] = ta1; rp[6] = ta2; rp[7] = ta3;
    }
    __syncthreads();
    if (tid < 128) {
        const int cq = tid >> 3;
        const int k  = tid & 7;
        const float v = red[0][cq][k] + red[1][cq][k] + red[2][cq][k] + red[3][cq][k];
        float* dstp = (k < 4) ? &sums[cq * 4 + k] : &sumsq[cq * 4 + (k - 4)];
        atomicAdd(dstp, v);
    }
}

// ---------------- fused: Qh_next = half( relu( relu(BN(Z)) @ W2 + b2 ) @ W1next ) ----------------
__global__ __launch_bounds__(256) void gemm2proj_kernel(const float* __restrict__ Z,
                                                        const float* __restrict__ sums,
                                                        const float* __restrict__ sumsq,
                                                        const float* __restrict__ g1,
                                                        const float* __restrict__ bt1,
                                                        const float* __restrict__ W2,   // [64][64]
                                                        const float* __restrict__ b2,
                                                        const float* __restrict__ W1n,  // [64][64]
                                                        __half2* __restrict__ QhOut)    // [N+1][32]
{
    __shared__ float sW2[64 * 64];
    __shared__ float sW1[64 * 64];
    __shared__ float sH[16 * 64];
    __shared__ float sA[16 * 64];
    __shared__ float sScale[64];
    __shared__ float sShift[64];
    const int tid = threadIdx.x;
    const int row0 = blockIdx.x * 16;

    if (tid < 64) {
        const float inv_n = 1.0f / (float)NN;
        const float mean = sums[tid] * inv_n;
        const float var = fmaxf(sumsq[tid] * inv_n - mean * mean, 0.f);
        const float sc = g1[tid] * rsqrtf(var + BN_EPS);
        sScale[tid] = sc;
        sShift[tid] = bt1[tid] - mean * sc;
    }
    for (int i = tid; i < 1024; i += 256) {
        ((float4*)sW2)[i] = ((const float4*)W2)[i];
        ((float4*)sW1)[i] = ((const float4*)W1n)[i];
    }
    __syncthreads();

    const f32x4* Zb = (const f32x4*)(Z + (size_t)row0 * 64);
    {
        const int i = tid;  // 256 float4s = 16 rows x 16
        const f32x4 z = __builtin_nontemporal_load(Zb + i);
        const int c4 = i & 15;
        const float4 sc = ((const float4*)sScale)[c4];
        const float4 sh = ((const float4*)sShift)[c4];
        float4 h;
        h.x = fmaxf(fmaf(z.x, sc.x, sh.x), 0.f);
        h.y = fmaxf(fmaf(z.y, sc.y, sh.y), 0.f);
        h.z = fmaxf(fmaf(z.z, sc.z, sh.z), 0.f);
        h.w = fmaxf(fmaf(z.w, sc.w, sh.w), 0.f);
        ((float4*)sH)[i] = h;
    }
    __syncthreads();

    // A = relu(H @ W2 + b2) -> sA
    {
        const int col = tid & 63;
        const int r0  = tid >> 6;
        const float bc = b2[col];
        float acc[4] = {bc, bc, bc, bc};
        for (int k = 0; k < 64; k += 4) {
            const float w0 = sW2[(k + 0) * 64 + col];
            const float w1 = sW2[(k + 1) * 64 + col];
            const float w2 = sW2[(k + 2) * 64 + col];
            const float w3 = sW2[(k + 3) * 64 + col];
#pragma unroll
            for (int rr = 0; rr < 4; ++rr) {
                const float4 hv = *(const float4*)&sH[(r0 + rr * 4) * 64 + k];
                acc[rr] = fmaf(hv.x, w0, acc[rr]);
                acc[rr] = fmaf(hv.y, w1, acc[rr]);
                acc[rr] = fmaf(hv.z, w2, acc[rr]);
                acc[rr] = fmaf(hv.w, w3, acc[rr]);
            }
        }
#pragma unroll
        for (int rr = 0; rr < 4; ++rr)
            sA[(r0 + rr * 4) * 64 + col] = fmaxf(acc[rr], 0.f);
    }
    __syncthreads();

    // Qh = half(A @ W1n)
    {
        const int col2 = tid & 31;   // column pair
        const int rg   = tid >> 5;   // 0..7 -> rows rg*2, rg*2+1
        float2 acc0 = {0.f, 0.f};
        float2 acc1 = {0.f, 0.f};
        const float* a0p = &sA[(rg * 2 + 0) * 64];
        const float* a1p = &sA[(rg * 2 + 1) * 64];
#pragma unroll 4
        for (int k = 0; k < 64; ++k) {
            const float2 w = *(const float2*)&sW1[k * 64 + col2 * 2];
            const float a0 = a0p[k];
            const float a1 = a1p[k];
            acc0.x = fmaf(a0, w.x, acc0.x);
            acc0.y = fmaf(a0, w.y, acc0.y);
            acc1.x = fmaf(a1, w.x, acc1.x);
            acc1.y = fmaf(a1, w.y, acc1.y);
        }
        const int r0 = row0 + rg * 2;
        QhOut[(size_t)(r0 + 0) * 32 + col2] = __floats2half2_rn(acc0.x, acc0.y);
        QhOut[(size_t)(r0 + 1) * 32 + col2] = __floats2half2_rn(acc1.x, acc1.y);
    }
}

// ---------------- gemm2 (pool epilogue, last layer) ----------------
__global__ __launch_bounds__(256) void gemm2pool_kernel(const float* __restrict__ Z,
                                                        const float* __restrict__ sums,
                                                        const float* __restrict__ sumsq,
                                                        const float* __restrict__ g1,
                                                        const float* __restrict__ bt1,
                                                        const float* __restrict__ W2,  // [64][64]
                                                        const float* __restrict__ b2,
                                                        const int* __restrict__ batch,
                                                        float* __restrict__ out)       // pooled [B][64]
{
    __shared__ float sW[64 * 64];
    __shared__ float sH[16 * 64];
    __shared__ float sScale[64];
    __shared__ float sShift[64];
    const int tid = threadIdx.x;
    const int row0 = blockIdx.x * 16;

    if (tid < 64) {
        const float inv_n = 1.0f / (float)NN;
        const float mean = sums[tid] * inv_n;
        const float var = fmaxf(sumsq[tid] * inv_n - mean * mean, 0.f);
        const float sc = g1[tid] * rsqrtf(var + BN_EPS);
        sScale[tid] = sc;
        sShift[tid] = bt1[tid] - mean * sc;
    }
    for (int i = tid; i < 1024; i += 256)
        ((float4*)sW)[i] = ((const float4*)W2)[i];
    __syncthreads();

    const f32x4* Zb = (const f32x4*)(Z + (size_t)row0 * 64);
    {
        const int i = tid;
        const f32x4 z = __builtin_nontemporal_load(Zb + i);
        const int c4 = i & 15;
        const float4 sc = ((const float4*)sScale)[c4];
        const float4 sh = ((const float4*)sShift)[c4];
        float4 h;
        h.x = fmaxf(fmaf(z.x, sc.x, sh.x), 0.f);
        h.y = fmaxf(fmaf(z.y, sc.y, sh.y), 0.f);
        h.z = fmaxf(fmaf(z.z, sc.z, sh.z), 0.f);
        h.w = fmaxf(fmaf(z.w, sc.w, sh.w), 0.f);
        ((float4*)sH)[i] = h;
    }
    __syncthreads();

    const int col = tid & 63;
    const int r0  = tid >> 6;
    const float bc = b2[col];
    float acc[4] = {bc, bc, bc, bc};
    for (int k = 0; k < 64; k += 4) {
        const float w0 = sW[(k + 0) * 64 + col];
        const float w1 = sW[(k + 1) * 64 + col];
        const float w2 = sW[(k + 2) * 64 + col];
        const float w3 = sW[(k + 3) * 64 + col];
#pragma unroll
        for (int rr = 0; rr < 4; ++rr) {
            const float4 hv = *(const float4*)&sH[(r0 + rr * 4) * 64 + k];
            acc[rr] = fmaf(hv.x, w0, acc[rr]);
            acc[rr] = fmaf(hv.y, w1, acc[rr]);
            acc[rr] = fmaf(hv.z, w2, acc[rr]);
            acc[rr] = fmaf(hv.w, w3, acc[rr]);
        }
    }
#pragma unroll
    for (int rr = 0; rr < 4; ++rr) {
        const int row = row0 + r0 + rr * 4;
        const float v = fmaxf(acc[rr], 0.f);
        atomicAdd(&out[(size_t)batch[row] * 64 + col], v);
    }
}

// ---------------- final MLP: out = relu(P @ fW1 + fb1) @ fW2 + fb2 ----------------
__global__ __launch_bounds__(256) void final_mlp(const float* __restrict__ P,   // [512][64]
                                                 const float* __restrict__ W1,  // [64][64]
                                                 const float* __restrict__ b1,
                                                 const float* __restrict__ W2,  // [64][32]
                                                 const float* __restrict__ b2,
                                                 float* __restrict__ out)       // [512][32]
{
    __shared__ float sW1[64 * 64];
    __shared__ float sW2[64 * 32];
    __shared__ float sH[4 * 64];
    const int tid = threadIdx.x;
    const int row0 = blockIdx.x * 4;

    for (int i = tid; i < 1024; i += 256) ((float4*)sW1)[i] = ((const float4*)W1)[i];
    for (int i = tid; i < 512; i += 256) ((float4*)sW2)[i] = ((const float4*)W2)[i];
    __syncthreads();

    const int col = tid & 63;
    const int r = tid >> 6;
    float acc = b1[col];
    const float* prow = P + (size_t)(row0 + r) * 64;
    for (int k = 0; k < 64; ++k) acc = fmaf(prow[k], sW1[k * 64 + col], acc);
    sH[r * 64 + col] = fmaxf(acc, 0.f);
    __syncthreads();

    if (tid < 128) {
        const int c = tid & 31;
        const int r2 = tid >> 5;
        float a2 = b2[c];
        for (int k = 0; k < 64; ++k) a2 = fmaf(sH[r2 * 64 + k], sW2[k * 32 + c], a2);
        out[(size_t)(row0 + r2) * 32 + c] = a2;
    }
}

extern "C" void kernel_launch(void* const* d_in, const int* in_sizes, int n_in,
                              void* d_out, int out_size, void* d_ws, size_t ws_size,
                              hipStream_t stream)
{
    const float* x   = (const float*)d_in[0];
    const int* ei    = (const int*)d_in[1];   // [2][E]: first E = src, next E = dst
    const int* batch = (const int*)d_in[2];
    const float* cW1[3] = {(const float*)d_in[4],  (const float*)d_in[10], (const float*)d_in[16]};
    const float* cb1[3] = {(const float*)d_in[5],  (const float*)d_in[11], (const float*)d_in[17]};
    const float* cg1[3] = {(const float*)d_in[6],  (const float*)d_in[12], (const float*)d_in[18]};
    const float* cbt[3] = {(const float*)d_in[7],  (const float*)d_in[13], (const float*)d_in[19]};
    const float* cW2[3] = {(const float*)d_in[8],  (const float*)d_in[14], (const float*)d_in[20]};
    const float* cb2[3] = {(const float*)d_in[9],  (const float*)d_in[15], (const float*)d_in[21]};
    const float* fW1 = (const float*)d_in[22];
    const float* fb1 = (const float*)d_in[23];
    const float* fW2 = (const float*)d_in[24];
    const float* fb2 = (const float*)d_in[25];
    float* out = (float*)d_out;

    // workspace layout
    float* bufX     = (float*)d_ws;                        // N*64 fp32: Z buffer
    __half2* Qh     = (__half2*)(bufX + (size_t)NN * 64);  // (N+1)*32 half2 (row NN = zero row)
    float* pooled   = (float*)(Qh + (size_t)(NN + 1) * 32);// B*64
    float* statsbuf = pooled + (size_t)BB * 64;            // 3 layers x (64 sums + 64 sumsq)
    int* deg        = (int*)(statsbuf + 384);              // N
    int* poffs      = deg + NN;                            // N+1 (padded offsets)
    int* blockSums  = poffs + (NN + 1);                    // 256
    int* blockOff   = blockSums + 256;                     // 256
    uintptr_t pa = ((uintptr_t)(blockOff + 256) + 15) & ~(uintptr_t)15;
    unsigned short* srcPadded = (unsigned short*)pa;       // PADMAX (16B aligned)
    unsigned short* rank      = srcPadded + PADMAX;        // E

    const int* esrc = ei;
    const int* edst = ei + EE;

    const int gemm_blocks = NN / 16;   // 3125
    const int edge_blocks = EE / 256;  // 3125

    // ---- build padded CSR by dst ----
    fill_kernel<<<(PADMAX / 2 + 255) / 256, 256, 0, stream>>>((unsigned int*)srcPadded, deg);
    hist_rank_kernel<<<edge_blocks, 256, 0, stream>>>(edst, deg, rank);
    scanA_kernel<<<SCAN_BLOCKS, 256, 0, stream>>>(deg, poffs, blockSums);
    scanB_kernel<<<1, 256, 0, stream>>>(blockSums, blockOff, poffs);
    scanC_kernel<<<SCAN_BLOCKS, 256, 0, stream>>>(poffs, blockOff, statsbuf, pooled,
                                                  (unsigned int*)(Qh + (size_t)NN * 32));
    scatter_kernel<<<edge_blocks, 256, 0, stream>>>(esrc, edst, rank, poffs, srcPadded);

    // layer 0 projection
    proj_kernel<DIN><<<gemm_blocks, 256, 0, stream>>>(x, cW1[0], Qh);

    for (int layer = 0; layer < 3; ++layer) {
        float* sums  = statsbuf + layer * 128;
        float* sumsq = sums + 64;

        // gather-aggregate + fused BN stats
        gather_kernel<<<GATHER_BLOCKS, 256, 0, stream>>>(Qh, poffs, srcPadded, cb1[layer],
                                                         bufX, sums, sumsq);

        if (layer < 2) {
            // BN + gemm2 + ReLU + next-layer proj, fused -> Qh
            gemm2proj_kernel<<<gemm_blocks, 256, 0, stream>>>(bufX, sums, sumsq, cg1[layer],
                                                              cbt[layer], cW2[layer], cb2[layer],
                                                              cW1[layer + 1], Qh);
        } else {
            gemm2pool_kernel<<<gemm_blocks, 256, 0, stream>>>(bufX, sums, sumsq, cg1[layer],
                                                              cbt[layer], cW2[layer], cb2[layer],
                                                              batch, pooled);
        }
    }

    // final MLP on pooled graph features
    final_mlp<<<BB / 4, 256, 0, stream>>>(pooled, fW1, fb1, fW2, fb2, out);
}

// Round 11
// 348.246 us; speedup vs baseline: 1.2011x; 1.0839x over previous
//
#include <hip/hip_runtime.h>
#include <hip/hip_fp16.h>

#define NN 50000
#define EE 800000
#define BB 512
#define DIN 128
#define HH 64
#define DOUT 32
#define BN_EPS 1e-5f
#define SCAN_BLOCKS 196    // ceil(50000/256)
#define GATHER_BLOCKS 1024
#define REGSZ 6250         // NN/8 nodes per XCD region
#define ECHUNK 3125        // EE/256 edges per scatter chunk

// ---------------- proj: Qh = half(X @ W)  (layer 0 only) ----------------
template <int CIN>
__global__ __launch_bounds__(256) void proj_kernel(const float* __restrict__ X,
                                                   const float* __restrict__ W,  // [CIN][64]
                                                   __half2* __restrict__ Qh)     // [N][32]
{
    __shared__ float sW[CIN * 64];
    __shared__ float sX[16 * CIN];
    const int tid = threadIdx.x;
    const int row0 = blockIdx.x * 16;

    for (int i = tid; i < CIN * 16; i += 256)
        ((float4*)sW)[i] = ((const float4*)W)[i];
    const float* Xb = X + (size_t)row0 * CIN;
    for (int i = tid; i < 16 * CIN / 4; i += 256)
        ((float4*)sX)[i] = ((const float4*)Xb)[i];
    __syncthreads();

    const int col2 = tid & 31;   // column pair
    const int rg   = tid >> 5;   // 0..7 -> rows rg*2, rg*2+1
    float2 acc0 = {0.f, 0.f};
    float2 acc1 = {0.f, 0.f};
    const float* x0p = &sX[(rg * 2 + 0) * CIN];
    const float* x1p = &sX[(rg * 2 + 1) * CIN];
#pragma unroll 4
    for (int k = 0; k < CIN; ++k) {
        const float2 w = *(const float2*)&sW[k * 64 + col2 * 2];
        const float x0 = x0p[k];
        const float x1 = x1p[k];
        acc0.x = fmaf(x0, w.x, acc0.x);
        acc0.y = fmaf(x0, w.y, acc0.y);
        acc1.x = fmaf(x1, w.x, acc1.x);
        acc1.y = fmaf(x1, w.y, acc1.y);
    }
    const int r0 = row0 + rg * 2;
    Qh[(size_t)(r0 + 0) * 32 + col2] = __floats2half2_rn(acc0.x, acc0.y);
    Qh[(size_t)(r0 + 1) * 32 + col2] = __floats2half2_rn(acc1.x, acc1.y);
}

// ---------------- CSR build ----------------
__global__ __launch_bounds__(256) void hist_rank_kernel(const int* __restrict__ dst,
                                                        int* __restrict__ deg,
                                                        unsigned short* __restrict__ rank)
{
    const int e = blockIdx.x * 256 + threadIdx.x;  // exactly E threads
    const int d = __builtin_nontemporal_load(dst + e);
    const unsigned short r = (unsigned short)atomicAdd(&deg[d], 1);
    __builtin_nontemporal_store(r, rank + e);
}

__global__ __launch_bounds__(256) void scanA_kernel(const int* __restrict__ deg,
                                                    int* __restrict__ offs,
                                                    int* __restrict__ blockSums)
{
    __shared__ int s[256];
    const int t = threadIdx.x;
    const int i = blockIdx.x * 256 + t;
    const int v = (i < NN) ? deg[i] : 0;
    s[t] = v;
    __syncthreads();
    for (int off = 1; off < 256; off <<= 1) {
        const int a = (t >= off) ? s[t - off] : 0;
        __syncthreads();
        s[t] += a;
        __syncthreads();
    }
    if (i < NN) offs[i] = s[t] - v;  // exclusive intra-block
    if (t == 255) blockSums[blockIdx.x] = s[255];
}

__global__ __launch_bounds__(256) void scanB_kernel(const int* __restrict__ blockSums,
                                                    int* __restrict__ blockOff)
{
    __shared__ int s[256];
    const int t = threadIdx.x;
    const int v = (t < SCAN_BLOCKS) ? blockSums[t] : 0;
    s[t] = v;
    __syncthreads();
    for (int off = 1; off < 256; off <<= 1) {
        const int a = (t >= off) ? s[t - off] : 0;
        __syncthreads();
        s[t] += a;
        __syncthreads();
    }
    if (t < SCAN_BLOCKS) blockOff[t] = s[t] - v;  // exclusive
}

__global__ __launch_bounds__(256) void scanC_kernel(int* __restrict__ offs,
                                                    const int* __restrict__ blockOff,
                                                    float* __restrict__ statsbuf,  // 384 floats
                                                    float* __restrict__ pooled)    // B*64
{
    const int i = blockIdx.x * 256 + threadIdx.x;
    if (i < NN) offs[i] += blockOff[blockIdx.x];
    if (i == 0) offs[NN] = EE;
    if (i < 384) statsbuf[i] = 0.f;
    if (i < BB * 64) pooled[i] = 0.f;
}

// XCD-partitioned scatter: region = blockIdx&7 (round-robin XCD heuristic). Each block streams
// one edge chunk and writes only edges whose dst lies in its node region -> every srcSorted
// line is written from a single XCD's L2 (written back once, no cross-XCD line bouncing).
__global__ __launch_bounds__(256) void scatter_kernel(const int* __restrict__ src,
                                                      const int* __restrict__ dst,
                                                      const unsigned short* __restrict__ rank,
                                                      const int* __restrict__ offs,
                                                      unsigned short* __restrict__ srcSorted)
{
    const int region = blockIdx.x & 7;
    const int chunk  = blockIdx.x >> 3;        // 0..255
    const int base   = chunk * ECHUNK;
    const int lo = region * REGSZ;
    for (int e = base + threadIdx.x; e < base + ECHUNK; e += 256) {
        const int d = __builtin_nontemporal_load(dst + e);
        if ((unsigned)(d - lo) < REGSZ) {
            const int s = src[e];
            const int r = (int)rank[e];
            srcSorted[offs[d] + r] = (unsigned short)s;
        }
    }
}

// ---------------- gather: Z[n] = Q[n] + b1 + sum_{src} Q[src]; fused BN column stats ----------------
// r4-verbatim structure (empirically fastest): 16 lanes per 128B row (uint2 = 8B/lane),
// grp=lane>>4 picks among 4 edges per load instruction; 16-edge main loop (4 row loads in
// flight per lane), 4-edge loop, predicated 1-edge tail. Plain (unpadded) CSR.
__global__ __launch_bounds__(256) void gather_kernel(const __half2* __restrict__ Qh,
                                                     const int* __restrict__ offs,
                                                     const unsigned short* __restrict__ srcSorted,
                                                     const float* __restrict__ b1,
                                                     float* __restrict__ Z,
                                                     float* __restrict__ sums,   // [64]
                                                     float* __restrict__ sumsq)  // [64]
{
    const int tid  = threadIdx.x;
    const int lane = tid & 63;
    const int wid  = tid >> 6;        // wave in block: 0..3
    const int colq = lane & 15;       // column quad (4 halfs = 8B)
    const int grp  = lane >> 4;       // 0..3: edge slot
    const uint2* Qr = (const uint2*)Qh;   // 16 uint2 per row
    const float4 bb = ((const float4*)b1)[colq];

    float sa0 = 0.f, sa1 = 0.f, sa2 = 0.f, sa3 = 0.f;
    float ta0 = 0.f, ta1 = 0.f, ta2 = 0.f, ta3 = 0.f;

    for (int node = blockIdx.x * 4 + wid; node < NN; node += GATHER_BLOCKS * 4) {
        const int o0 = offs[node];
        const int o1 = offs[node + 1];
        float a0 = 0.f, a1 = 0.f, a2 = 0.f, a3 = 0.f;
        int j = o0;
        for (; j + 16 <= o1; j += 16) {
            const int e0 = srcSorted[j + grp];
            const int e1 = srcSorted[j + 4 + grp];
            const int e2 = srcSorted[j + 8 + grp];
            const int e3 = srcSorted[j + 12 + grp];
            const uint2 r0 = Qr[(size_t)e0 * 16 + colq];
            const uint2 r1 = Qr[(size_t)e1 * 16 + colq];
            const uint2 r2 = Qr[(size_t)e2 * 16 + colq];
            const uint2 r3 = Qr[(size_t)e3 * 16 + colq];
            float2 p;
            p = __half22float2(*(const __half2*)&r0.x); a0 += p.x; a1 += p.y;
            p = __half22float2(*(const __half2*)&r0.y); a2 += p.x; a3 += p.y;
            p = __half22float2(*(const __half2*)&r1.x); a0 += p.x; a1 += p.y;
            p = __half22float2(*(const __half2*)&r1.y); a2 += p.x; a3 += p.y;
            p = __half22float2(*(const __half2*)&r2.x); a0 += p.x; a1 += p.y;
            p = __half22float2(*(const __half2*)&r2.y); a2 += p.x; a3 += p.y;
            p = __half22float2(*(const __half2*)&r3.x); a0 += p.x; a1 += p.y;
            p = __half22float2(*(const __half2*)&r3.y); a2 += p.x; a3 += p.y;
        }
        for (; j + 4 <= o1; j += 4) {
            const int e0 = srcSorted[j + grp];
            const uint2 r0 = Qr[(size_t)e0 * 16 + colq];
            float2 p;
            p = __half22float2(*(const __half2*)&r0.x); a0 += p.x; a1 += p.y;
            p = __half22float2(*(const __half2*)&r0.y); a2 += p.x; a3 += p.y;
        }
        if (grp < o1 - j) {
            const int e0 = srcSorted[j + grp];
            const uint2 r0 = Qr[(size_t)e0 * 16 + colq];
            float2 p;
            p = __half22float2(*(const __half2*)&r0.x); a0 += p.x; a1 += p.y;
            p = __half22float2(*(const __half2*)&r0.y); a2 += p.x; a3 += p.y;
        }
        // combine the 4 edge-groups
        a0 += __shfl_xor(a0, 16); a1 += __shfl_xor(a1, 16);
        a2 += __shfl_xor(a2, 16); a3 += __shfl_xor(a3, 16);
        a0 += __shfl_xor(a0, 32); a1 += __shfl_xor(a1, 32);
        a2 += __shfl_xor(a2, 32); a3 += __shfl_xor(a3, 32);
        if (grp == 0) {
            const uint2 sr = Qr[(size_t)node * 16 + colq];
            float2 p;
            p = __half22float2(*(const __half2*)&sr.x); a0 += p.x + bb.x; a1 += p.y + bb.y;
            p = __half22float2(*(const __half2*)&sr.y); a2 += p.x + bb.z; a3 += p.y + bb.w;
            float4 zv = {a0, a1, a2, a3};
            ((float4*)Z)[(size_t)node * 16 + colq] = zv;
            sa0 += a0; sa1 += a1; sa2 += a2; sa3 += a3;
            ta0 += a0 * a0; ta1 += a1 * a1; ta2 += a2 * a2; ta3 += a3 * a3;
        }
    }

    // block-level stats reduce: 4 waves x 16 colq x 8 values -> 128 atomics
    __shared__ float red[4][16][8];
    if (grp == 0) {
        float* rp = red[wid][colq];
        rp[0] = sa0; rp[1] = sa1; rp[2] = sa2; rp[3] = sa3;
        rp[4] = ta0; rp[5] = ta1; rp[6] = ta2; rp[7] = ta3;
    }
    __syncthreads();
    if (tid < 128) {
        const int cq = tid >> 3;
        const int k  = tid & 7;
        const float v = red[0][cq][k] + red[1][cq][k] + red[2][cq][k] + red[3][cq][k];
        float* dstp = (k < 4) ? &sums[cq * 4 + k] : &sumsq[cq * 4 + (k - 4)];
        atomicAdd(dstp, v);
    }
}

// ---------------- fused: Qh_next = half( relu( relu(BN(Z)) @ W2 + b2 ) @ W1next ) ----------------
__global__ __launch_bounds__(256) void gemm2proj_kernel(const float* __restrict__ Z,
                                                        const float* __restrict__ sums,
                                                        const float* __restrict__ sumsq,
                                                        const float* __restrict__ g1,
                                                        const float* __restrict__ bt1,
                                                        const float* __restrict__ W2,   // [64][64]
                                                        const float* __restrict__ b2,
                                                        const float* __restrict__ W1n,  // [64][64]
                                                        __half2* __restrict__ QhOut)    // [N][32]
{
    __shared__ float sW2[64 * 64];
    __shared__ float sW1[64 * 64];
    __shared__ float sH[16 * 64];
    __shared__ float sA[16 * 64];
    __shared__ float sScale[64];
    __shared__ float sShift[64];
    const int tid = threadIdx.x;
    const int row0 = blockIdx.x * 16;

    if (tid < 64) {
        const float inv_n = 1.0f / (float)NN;
        const float mean = sums[tid] * inv_n;
        const float var = fmaxf(sumsq[tid] * inv_n - mean * mean, 0.f);
        const float sc = g1[tid] * rsqrtf(var + BN_EPS);
        sScale[tid] = sc;
        sShift[tid] = bt1[tid] - mean * sc;
    }
    for (int i = tid; i < 1024; i += 256) {
        ((float4*)sW2)[i] = ((const float4*)W2)[i];
        ((float4*)sW1)[i] = ((const float4*)W1n)[i];
    }
    __syncthreads();

    const float4* Zb = (const float4*)(Z + (size_t)row0 * 64);
    {
        const int i = tid;  // 256 float4s = 16 rows x 16
        const float4 z = Zb[i];
        const int c4 = i & 15;
        const float4 sc = ((const float4*)sScale)[c4];
        const float4 sh = ((const float4*)sShift)[c4];
        float4 h;
        h.x = fmaxf(fmaf(z.x, sc.x, sh.x), 0.f);
        h.y = fmaxf(fmaf(z.y, sc.y, sh.y), 0.f);
        h.z = fmaxf(fmaf(z.z, sc.z, sh.z), 0.f);
        h.w = fmaxf(fmaf(z.w, sc.w, sh.w), 0.f);
        ((float4*)sH)[i] = h;
    }
    __syncthreads();

    // A = relu(H @ W2 + b2) -> sA
    {
        const int col = tid & 63;
        const int r0  = tid >> 6;
        const float bc = b2[col];
        float acc[4] = {bc, bc, bc, bc};
        for (int k = 0; k < 64; k += 4) {
            const float w0 = sW2[(k + 0) * 64 + col];
            const float w1 = sW2[(k + 1) * 64 + col];
            const float w2 = sW2[(k + 2) * 64 + col];
            const float w3 = sW2[(k + 3) * 64 + col];
#pragma unroll
            for (int rr = 0; rr < 4; ++rr) {
                const float4 hv = *(const float4*)&sH[(r0 + rr * 4) * 64 + k];
                acc[rr] = fmaf(hv.x, w0, acc[rr]);
                acc[rr] = fmaf(hv.y, w1, acc[rr]);
                acc[rr] = fmaf(hv.z, w2, acc[rr]);
                acc[rr] = fmaf(hv.w, w3, acc[rr]);
            }
        }
#pragma unroll
        for (int rr = 0; rr < 4; ++rr)
            sA[(r0 + rr * 4) * 64 + col] = fmaxf(acc[rr], 0.f);
    }
    __syncthreads();

    // Qh = half(A @ W1n)
    {
        const int col2 = tid & 31;   // column pair
        const int rg   = tid >> 5;   // 0..7 -> rows rg*2, rg*2+1
        float2 acc0 = {0.f, 0.f};
        float2 acc1 = {0.f, 0.f};
        const float* a0p = &sA[(rg * 2 + 0) * 64];
        const float* a1p = &sA[(rg * 2 + 1) * 64];
#pragma unroll 4
        for (int k = 0; k < 64; ++k) {
            const float2 w = *(const float2*)&sW1[k * 64 + col2 * 2];
            const float a0 = a0p[k];
            const float a1 = a1p[k];
            acc0.x = fmaf(a0, w.x, acc0.x);
            acc0.y = fmaf(a0, w.y, acc0.y);
            acc1.x = fmaf(a1, w.x, acc1.x);
            acc1.y = fmaf(a1, w.y, acc1.y);
        }
        const int r0 = row0 + rg * 2;
        QhOut[(size_t)(r0 + 0) * 32 + col2] = __floats2half2_rn(acc0.x, acc0.y);
        QhOut[(size_t)(r0 + 1) * 32 + col2] = __floats2half2_rn(acc1.x, acc1.y);
    }
}

// ---------------- gemm2 (pool epilogue, last layer) ----------------
__global__ __launch_bounds__(256) void gemm2pool_kernel(const float* __restrict__ Z,
                                                        const float* __restrict__ sums,
                                                        const float* __restrict__ sumsq,
                                                        const float* __restrict__ g1,
                                                        const float* __restrict__ bt1,
                                                        const float* __restrict__ W2,  // [64][64]
                                                        const float* __restrict__ b2,
                                                        const int* __restrict__ batch,
                                                        float* __restrict__ out)       // pooled [B][64]
{
    __shared__ float sW[64 * 64];
    __shared__ float sH[16 * 64];
    __shared__ float sScale[64];
    __shared__ float sShift[64];
    const int tid = threadIdx.x;
    const int row0 = blockIdx.x * 16;

    if (tid < 64) {
        const float inv_n = 1.0f / (float)NN;
        const float mean = sums[tid] * inv_n;
        const float var = fmaxf(sumsq[tid] * inv_n - mean * mean, 0.f);
        const float sc = g1[tid] * rsqrtf(var + BN_EPS);
        sScale[tid] = sc;
        sShift[tid] = bt1[tid] - mean * sc;
    }
    for (int i = tid; i < 1024; i += 256)
        ((float4*)sW)[i] = ((const float4*)W2)[i];
    __syncthreads();

    const float4* Zb = (const float4*)(Z + (size_t)row0 * 64);
    {
        const int i = tid;
        const float4 z = Zb[i];
        const int c4 = i & 15;
        const float4 sc = ((const float4*)sScale)[c4];
        const float4 sh = ((const float4*)sShift)[c4];
        float4 h;
        h.x = fmaxf(fmaf(z.x, sc.x, sh.x), 0.f);
        h.y = fmaxf(fmaf(z.y, sc.y, sh.y), 0.f);
        h.z = fmaxf(fmaf(z.z, sc.z, sh.z), 0.f);
        h.w = fmaxf(fmaf(z.w, sc.w, sh.w), 0.f);
        ((float4*)sH)[i] = h;
    }
    __syncthreads();

    const int col = tid & 63;
    const int r0  = tid >> 6;
    const float bc = b2[col];
    float acc[4] = {bc, bc, bc, bc};
    for (int k = 0; k < 64; k += 4) {
        const float w0 = sW[(k + 0) * 64 + col];
        const float w1 = sW[(k + 1) * 64 + col];
        const float w2 = sW[(k + 2) * 64 + col];
        const float w3 = sW[(k + 3) * 64 + col];
#pragma unroll
        for (int rr = 0; rr < 4; ++rr) {
            const float4 hv = *(const float4*)&sH[(r0 + rr * 4) * 64 + k];
            acc[rr] = fmaf(hv.x, w0, acc[rr]);
            acc[rr] = fmaf(hv.y, w1, acc[rr]);
            acc[rr] = fmaf(hv.z, w2, acc[rr]);
            acc[rr] = fmaf(hv.w, w3, acc[rr]);
        }
    }
#pragma unroll
    for (int rr = 0; rr < 4; ++rr) {
        const int row = row0 + r0 + rr * 4;
        const float v = fmaxf(acc[rr], 0.f);
        atomicAdd(&out[(size_t)batch[row] * 64 + col], v);
    }
}

// ---------------- final MLP: out = relu(P @ fW1 + fb1) @ fW2 + fb2 ----------------
__global__ __launch_bounds__(256) void final_mlp(const float* __restrict__ P,   // [512][64]
                                                 const float* __restrict__ W1,  // [64][64]
                                                 const float* __restrict__ b1,
                                                 const float* __restrict__ W2,  // [64][32]
                                                 const float* __restrict__ b2,
                                                 float* __restrict__ out)       // [512][32]
{
    __shared__ float sW1[64 * 64];
    __shared__ float sW2[64 * 32];
    __shared__ float sH[4 * 64];
    const int tid = threadIdx.x;
    const int row0 = blockIdx.x * 4;

    for (int i = tid; i < 1024; i += 256) ((float4*)sW1)[i] = ((const float4*)W1)[i];
    for (int i = tid; i < 512; i += 256) ((float4*)sW2)[i] = ((const float4*)W2)[i];
    __syncthreads();

    const int col = tid & 63;
    const int r = tid >> 6;
    float acc = b1[col];
    const float* prow = P + (size_t)(row0 + r) * 64;
    for (int k = 0; k < 64; ++k) acc = fmaf(prow[k], sW1[k * 64 + col], acc);
    sH[r * 64 + col] = fmaxf(acc, 0.f);
    __syncthreads();

    if (tid < 128) {
        const int c = tid & 31;
        const int r2 = tid >> 5;
        float a2 = b2[c];
        for (int k = 0; k < 64; ++k) a2 = fmaf(sH[r2 * 64 + k], sW2[k * 32 + c], a2);
        out[(size_t)(row0 + r2) * 32 + c] = a2;
    }
}

extern "C" void kernel_launch(void* const* d_in, const int* in_sizes, int n_in,
                              void* d_out, int out_size, void* d_ws, size_t ws_size,
                              hipStream_t stream)
{
    const float* x   = (const float*)d_in[0];
    const int* ei    = (const int*)d_in[1];   // [2][E]: first E = src, next E = dst
    const int* batch = (const int*)d_in[2];
    const float* cW1[3] = {(const float*)d_in[4],  (const float*)d_in[10], (const float*)d_in[16]};
    const float* cb1[3] = {(const float*)d_in[5],  (const float*)d_in[11], (const float*)d_in[17]};
    const float* cg1[3] = {(const float*)d_in[6],  (const float*)d_in[12], (const float*)d_in[18]};
    const float* cbt[3] = {(const float*)d_in[7],  (const float*)d_in[13], (const float*)d_in[19]};
    const float* cW2[3] = {(const float*)d_in[8],  (const float*)d_in[14], (const float*)d_in[20]};
    const float* cb2[3] = {(const float*)d_in[9],  (const float*)d_in[15], (const float*)d_in[21]};
    const float* fW1 = (const float*)d_in[22];
    const float* fb1 = (const float*)d_in[23];
    const float* fW2 = (const float*)d_in[24];
    const float* fb2 = (const float*)d_in[25];
    float* out = (float*)d_out;

    // workspace layout
    float* bufX     = (float*)d_ws;                        // N*64 fp32: Z buffer
    __half2* Qh     = (__half2*)(bufX + (size_t)NN * 64);  // N*32 half2
    float* pooled   = (float*)(Qh + (size_t)NN * 32);      // B*64
    float* statsbuf = pooled + (size_t)BB * 64;            // 3 layers x (64 sums + 64 sumsq)
    int* deg        = (int*)(statsbuf + 384);              // N
    int* offs       = deg + NN;                            // N+1
    int* blockSums  = offs + (NN + 1);                     // 256
    int* blockOff   = blockSums + 256;                     // 256
    unsigned short* rank      = (unsigned short*)(blockOff + 256);  // E
    unsigned short* srcSorted = rank + EE;                          // E (+pad)

    const int* esrc = ei;
    const int* edst = ei + EE;

    const int gemm_blocks = NN / 16;   // 3125
    const int edge_blocks = EE / 256;  // 3125

    // ---- build CSR by dst ----
    hipMemsetAsync(deg, 0, NN * sizeof(int), stream);
    hist_rank_kernel<<<edge_blocks, 256, 0, stream>>>(edst, deg, rank);
    scanA_kernel<<<SCAN_BLOCKS, 256, 0, stream>>>(deg, offs, blockSums);
    scanB_kernel<<<1, 256, 0, stream>>>(blockSums, blockOff);
    scanC_kernel<<<SCAN_BLOCKS, 256, 0, stream>>>(offs, blockOff, statsbuf, pooled);
    scatter_kernel<<<2048, 256, 0, stream>>>(esrc, edst, rank, offs, srcSorted);

    // layer 0 projection
    proj_kernel<DIN><<<gemm_blocks, 256, 0, stream>>>(x, cW1[0], Qh);

    for (int layer = 0; layer < 3; ++layer) {
        float* sums  = statsbuf + layer * 128;
        float* sumsq = sums + 64;

        // gather-aggregate + fused BN stats
        gather_kernel<<<GATHER_BLOCKS, 256, 0, stream>>>(Qh, offs, srcSorted, cb1[layer],
                                                         bufX, sums, sumsq);

        if (layer < 2) {
            // BN + gemm2 + ReLU + next-layer proj, fused -> Qh
            gemm2proj_kernel<<<gemm_blocks, 256, 0, stream>>>(bufX, sums, sumsq, cg1[layer],
                                                              cbt[layer], cW2[layer], cb2[layer],
                                                              cW1[layer + 1], Qh);
        } else {
            gemm2pool_kernel<<<gemm_blocks, 256, 0, stream>>>(bufX, sums, sumsq, cg1[layer],
                                                              cbt[layer], cW2[layer], cb2[layer],
                                                              batch, pooled);
        }
    }

    // final MLP on pooled graph features
    final_mlp<<<BB / 4, 256, 0, stream>>>(pooled, fW1, fb1, fW2, fb2, out);
}